// Round 4
// baseline (490.044 us; speedup 1.0000x reference)
//
#include <hip/hip_runtime.h>

constexpr int N_NODES = 100000;
constexpr int N_EDGES = 1600000;
constexpr int IN_DIM  = 128;
constexpr int HID     = 64;
constexpr int C2      = 8;
constexpr int GDIM    = 24;
constexpr int NG      = 64;
constexpr float SLOPE = 0.01f;
constexpr int NB_SCAN = (N_NODES + 255) / 256;   // 391

__device__ __forceinline__ float lrelu(float v) { return v > 0.f ? v : SLOPE * v; }

__device__ __forceinline__ float bf2f(unsigned short u) {
    union { unsigned int i; float f; } c;
    c.i = ((unsigned int)u) << 16;
    return c.f;
}
__device__ __forceinline__ unsigned short f2bf(float f) {
    unsigned int i = __float_as_uint(f);
    unsigned int r = (i + 0x7fffu + ((i >> 16) & 1u)) >> 16;   // RNE
    return (unsigned short)r;
}

// ---- rank pass: deg histogram + per-edge rank in one pass ----
__global__ void k_rank(const int* __restrict__ dst, int* __restrict__ deg,
                       int* __restrict__ rnk) {
    int e = blockIdx.x * 256 + threadIdx.x;
    if (e < N_EDGES) rnk[e] = atomicAdd(&deg[dst[e]], 1);
}

// ---- scan1: block-local exclusive scan of deg + dinv ----
__global__ void k_scan1(const int* __restrict__ deg, int* __restrict__ rowptr,
                        int* __restrict__ bsum, float* __restrict__ dinv) {
    __shared__ int s[256];
    int tid = threadIdx.x;
    int i = blockIdx.x * 256 + tid;
    int v = (i < N_NODES) ? deg[i] : 0;
    if (i < N_NODES) dinv[i] = rsqrtf((float)(v + 1));
    s[tid] = v;
    __syncthreads();
    for (int off = 1; off < 256; off <<= 1) {
        int t = (tid >= off) ? s[tid - off] : 0;
        __syncthreads();
        s[tid] += t;
        __syncthreads();
    }
    if (i < N_NODES) rowptr[i] = s[tid] - v;   // block-local exclusive
    if (tid == 255) bsum[blockIdx.x] = s[255];
}

// ---- scan2: exclusive scan of block sums + zero pool accumulators ----
__global__ void k_scan2(const int* __restrict__ bsum, int* __restrict__ bsumx,
                        float* __restrict__ gacc) {
    __shared__ int s[512];
    int tid = threadIdx.x;
    for (int j = tid; j < NG * C2 + NG; j += 512) gacc[j] = 0.f;
    int v = (tid < NB_SCAN) ? bsum[tid] : 0;
    s[tid] = v;
    __syncthreads();
    for (int off = 1; off < 512; off <<= 1) {
        int t = (tid >= off) ? s[tid - off] : 0;
        __syncthreads();
        s[tid] += t;
        __syncthreads();
    }
    if (tid < NB_SCAN) bsumx[tid] = s[tid] - v;
}

// ---- place: atomic-free scatter using precomputed ranks ----
__global__ void k_place(const int* __restrict__ src, const int* __restrict__ dst,
                        const int* __restrict__ rnk, const int* __restrict__ rowptr,
                        const int* __restrict__ bsumx, int* __restrict__ eidx) {
    int e = blockIdx.x * 256 + threadIdx.x;
    if (e < N_EDGES) {
        int d = dst[e];
        eidx[rowptr[d] + bsumx[d >> 8] + rnk[e]] = src[e];
    }
}

// ---- layer-1 GEMM: hs1(bf16)[n,:] = (x[n,:] @ W1) * dinv[n] ----
__global__ __launch_bounds__(256) void k_gemm1(const float* __restrict__ x,
                                               const float* __restrict__ W1,
                                               const float* __restrict__ dinv,
                                               unsigned short* __restrict__ hs1) {
    __shared__ float sW[IN_DIM * HID];   // 32 KiB
    __shared__ float sX[32][IN_DIM];     // 16 KiB
    int node0 = blockIdx.x * 32;         // 3125 * 32 == 100000
    for (int t = threadIdx.x; t < IN_DIM * HID / 4; t += 256)
        ((float4*)sW)[t] = ((const float4*)W1)[t];
    for (int t = threadIdx.x; t < 32 * IN_DIM / 4; t += 256) {
        int r = t >> 5, c4 = t & 31;
        ((float4*)&sX[r][0])[c4] = ((const float4*)(x + (size_t)(node0 + r) * IN_DIM))[c4];
    }
    __syncthreads();
    int col = threadIdx.x & 63;
    int nb  = (threadIdx.x >> 6) * 8;
    float acc[8] = {0.f, 0.f, 0.f, 0.f, 0.f, 0.f, 0.f, 0.f};
    for (int k4 = 0; k4 < IN_DIM; k4 += 4) {
        float w0 = sW[(k4 + 0) * HID + col];
        float w1 = sW[(k4 + 1) * HID + col];
        float w2 = sW[(k4 + 2) * HID + col];
        float w3 = sW[(k4 + 3) * HID + col];
#pragma unroll
        for (int j = 0; j < 8; ++j) {
            float4 xv = *((const float4*)&sX[nb + j][k4]);
            acc[j] += xv.x * w0 + xv.y * w1 + xv.z * w2 + xv.w * w3;
        }
    }
#pragma unroll
    for (int j = 0; j < 8; ++j) {
        int n = node0 + nb + j;
        hs1[(size_t)n * HID + col] = f2bf(acc[j] * dinv[n]);
    }
}

// ---- layer-1 aggregate (bf16 gather) + epilogue + fused layer-2 GEMM ----
__global__ __launch_bounds__(256) void k_agg1(const int* __restrict__ rowptr,
                                              const int* __restrict__ bsumx,
                                              const int* __restrict__ deg,
                                              const int* __restrict__ eidx,
                                              const unsigned short* __restrict__ hs1,
                                              const float* __restrict__ dinv,
                                              const float* __restrict__ b1,
                                              const float* __restrict__ W2,
                                              float* __restrict__ hs2) {
    __shared__ float sW2t[C2 * HID];     // [j][k] transposed
    for (int i = threadIdx.x; i < C2 * HID; i += 256) {
        int j = i >> 6, k = i & 63;
        sW2t[i] = W2[k * C2 + j];        // consecutive LDS writes: conflict-free
    }
    __syncthreads();
    int node = blockIdx.x * 4 + (threadIdx.x >> 6);   // 25000 * 4 == 100000
    int lane = threadIdx.x & 63;
    int q    = lane & 15;
    int slot = lane >> 4;
    int start = rowptr[node] + bsumx[node >> 8];
    int cnt   = deg[node];
    float4 acc = make_float4(0.f, 0.f, 0.f, 0.f);
    for (int k = slot; k < cnt; k += 4) {
        int s = eidx[start + k];
        ushort4 v = ((const ushort4*)(hs1 + (size_t)s * HID))[q];
        acc.x += bf2f(v.x); acc.y += bf2f(v.y);
        acc.z += bf2f(v.z); acc.w += bf2f(v.w);
    }
    acc.x += __shfl_xor(acc.x, 16); acc.y += __shfl_xor(acc.y, 16);
    acc.z += __shfl_xor(acc.z, 16); acc.w += __shfl_xor(acc.w, 16);
    acc.x += __shfl_xor(acc.x, 32); acc.y += __shfl_xor(acc.y, 32);
    acc.z += __shfl_xor(acc.z, 32); acc.w += __shfl_xor(acc.w, 32);
    ushort4 hv = ((const ushort4*)(hs1 + (size_t)node * HID))[q];
    float  di = dinv[node];
    float4 bb = ((const float4*)b1)[q];
    float4 y;
    y.x = lrelu(di * (acc.x + bf2f(hv.x)) + bb.x);
    y.y = lrelu(di * (acc.y + bf2f(hv.y)) + bb.y);
    y.z = lrelu(di * (acc.z + bf2f(hv.z)) + bb.z);
    y.w = lrelu(di * (acc.w + bf2f(hv.w)) + bb.w);
    // fused gemm2: slot s computes outputs j0=2s, j0+1
    int j0 = slot * 2;
    const float* w0 = sW2t + j0 * HID + 4 * q;
    const float* w1 = w0 + HID;
    float p0 = y.x * w0[0] + y.y * w0[1] + y.z * w0[2] + y.w * w0[3];
    float p1 = y.x * w1[0] + y.y * w1[1] + y.z * w1[2] + y.w * w1[3];
#pragma unroll
    for (int m = 1; m < 16; m <<= 1) {
        p0 += __shfl_xor(p0, m);
        p1 += __shfl_xor(p1, m);
    }
    if (q == 0) {
        float2 r; r.x = p0 * di; r.y = p1 * di;
        ((float2*)(hs2 + (size_t)node * C2))[slot] = r;
    }
}

// ---- layer-2 aggregate + epilogue + FUSED mean-pool ----
__global__ __launch_bounds__(256) void k_agg2(const int* __restrict__ rowptr,
                                              const int* __restrict__ bsumx,
                                              const int* __restrict__ deg,
                                              const int* __restrict__ eidx,
                                              const float* __restrict__ hs2,
                                              const float* __restrict__ dinv,
                                              const float* __restrict__ b2,
                                              const int* __restrict__ batch,
                                              float* __restrict__ gsum,
                                              float* __restrict__ gcnt) {
    __shared__ float ssum[NG * C2];
    __shared__ float scnt[NG];
    for (int i = threadIdx.x; i < NG * C2; i += 256) ssum[i] = 0.f;
    for (int i = threadIdx.x; i < NG; i += 256) scnt[i] = 0.f;
    __syncthreads();
    int node = blockIdx.x * 4 + (threadIdx.x >> 6);
    int lane = threadIdx.x & 63;
    int q    = lane & 1;
    int slot = lane >> 1;
    int start = rowptr[node] + bsumx[node >> 8];
    int cnt   = deg[node];
    float4 acc = make_float4(0.f, 0.f, 0.f, 0.f);
    for (int k = slot; k < cnt; k += 32) {
        int s = eidx[start + k];
        float4 v = ((const float4*)(hs2 + (size_t)s * C2))[q];
        acc.x += v.x; acc.y += v.y; acc.z += v.z; acc.w += v.w;
    }
    for (int m = 2; m < 64; m <<= 1) {
        acc.x += __shfl_xor(acc.x, m); acc.y += __shfl_xor(acc.y, m);
        acc.z += __shfl_xor(acc.z, m); acc.w += __shfl_xor(acc.w, m);
    }
    if (slot == 0) {
        float4 h = ((const float4*)(hs2 + (size_t)node * C2))[q];
        float di = dinv[node];
        const float* bb = b2 + q * 4;
        int g = batch[node];
        float* sb = ssum + g * C2 + q * 4;
        atomicAdd(sb + 0, lrelu(di * (acc.x + h.x) + bb[0]));
        atomicAdd(sb + 1, lrelu(di * (acc.y + h.y) + bb[1]));
        atomicAdd(sb + 2, lrelu(di * (acc.z + h.z) + bb[2]));
        atomicAdd(sb + 3, lrelu(di * (acc.w + h.w) + bb[3]));
        if (q == 0) atomicAdd(&scnt[g], 1.f);
    }
    __syncthreads();
    for (int i = threadIdx.x; i < NG * C2; i += 256)
        if (ssum[i] != 0.f) atomicAdd(&gsum[i], ssum[i]);
    for (int i = threadIdx.x; i < NG; i += 256)
        if (scnt[i] != 0.f) atomicAdd(&gcnt[i], scnt[i]);
}

// ---- final MLP ----
__global__ void k_mlp(const float* __restrict__ gsum, const float* __restrict__ gcnt,
                      const float* __restrict__ gfeat,
                      const float* __restrict__ fcW1, const float* __restrict__ fcb1,
                      const float* __restrict__ fcW2, const float* __restrict__ fcb2,
                      float* __restrict__ out) {
    int g = threadIdx.x;
    if (g >= NG) return;
    float z[C2 + GDIM];
    float cnt = fmaxf(gcnt[g], 1.f);
    for (int c = 0; c < C2; ++c) z[c] = gsum[g * C2 + c] / cnt;
    for (int c = 0; c < GDIM; ++c) z[C2 + c] = gfeat[g * GDIM + c];
    float h16[16];
    for (int j = 0; j < 16; ++j) {
        float acc = fcb1[j];
        for (int c = 0; c < C2 + GDIM; ++c) acc += z[c] * fcW1[c * 16 + j];
        h16[j] = lrelu(acc);
    }
    float acc = fcb2[0];
    for (int j = 0; j < 16; ++j) acc += h16[j] * fcW2[j];
    out[g] = lrelu(acc);
}

extern "C" void kernel_launch(void* const* d_in, const int* in_sizes, int n_in,
                              void* d_out, int out_size, void* d_ws, size_t ws_size,
                              hipStream_t stream) {
    const float* x     = (const float*)d_in[0];
    const int*   ei    = (const int*)d_in[1];
    const int*   batch = (const int*)d_in[2];
    const float* gfeat = (const float*)d_in[3];
    const float* W1    = (const float*)d_in[4];
    const float* b1    = (const float*)d_in[5];
    const float* W2    = (const float*)d_in[6];
    const float* b2    = (const float*)d_in[7];
    const float* fcW1  = (const float*)d_in[8];
    const float* fcb1  = (const float*)d_in[9];
    const float* fcW2  = (const float*)d_in[10];
    const float* fcb2  = (const float*)d_in[11];
    const int* src = ei;
    const int* dst = ei + N_EDGES;

    char* ws = (char*)d_ws;
    size_t off = 0;
    auto alloc = [&](size_t bytes) -> void* {
        void* p = ws + off;
        off = (off + bytes + 255) & ~(size_t)255;
        return p;
    };
    int*   deg    = (int*)  alloc((size_t)N_NODES * 4);
    float* dinv   = (float*)alloc((size_t)N_NODES * 4);
    int*   rowptr = (int*)  alloc((size_t)N_NODES * 4);
    int*   bsum   = (int*)  alloc(512 * 4);
    int*   bsumx  = (int*)  alloc(512 * 4);
    int*   rnk    = (int*)  alloc((size_t)N_EDGES * 4);
    int*   eidx   = (int*)  alloc((size_t)N_EDGES * 4);
    unsigned short* hs1 = (unsigned short*)alloc((size_t)N_NODES * HID * 2);
    float* hs2    = (float*)alloc((size_t)N_NODES * C2 * 4);
    float* gacc   = (float*)alloc((size_t)(NG * C2 + NG) * 4);
    float* gsum   = gacc;
    float* gcnt   = gacc + NG * C2;

    hipMemsetAsync(deg, 0, (size_t)N_NODES * 4, stream);

    k_rank <<<(N_EDGES + 255) / 256, 256, 0, stream>>>(dst, deg, rnk);
    k_scan1<<<NB_SCAN, 256, 0, stream>>>(deg, rowptr, bsum, dinv);
    k_scan2<<<1, 512, 0, stream>>>(bsum, bsumx, gacc);
    k_place<<<(N_EDGES + 255) / 256, 256, 0, stream>>>(src, dst, rnk, rowptr, bsumx, eidx);

    k_gemm1<<<N_NODES / 32, 256, 0, stream>>>(x, W1, dinv, hs1);
    k_agg1 <<<N_NODES / 4, 256, 0, stream>>>(rowptr, bsumx, deg, eidx, hs1, dinv, b1, W2, hs2);
    k_agg2 <<<N_NODES / 4, 256, 0, stream>>>(rowptr, bsumx, deg, eidx, hs2, dinv, b2, batch, gsum, gcnt);
    k_mlp  <<<1, 64, 0, stream>>>(gsum, gcnt, gfeat, fcW1, fcb1, fcW2, fcb2, (float*)d_out);
}

// Round 5
// 298.947 us; speedup vs baseline: 1.6392x; 1.6392x over previous
//
#include <hip/hip_runtime.h>

constexpr int N_NODES = 100000;
constexpr int N_EDGES = 1600000;
constexpr int IN_DIM  = 128;
constexpr int HID     = 64;
constexpr int C2      = 8;
constexpr int GDIM    = 24;
constexpr int NG      = 64;
constexpr float SLOPE = 0.01f;
constexpr int NB_SCAN = (N_NODES + 255) / 256;   // 391

__device__ __forceinline__ float lrelu(float v) { return v > 0.f ? v : SLOPE * v; }

__device__ __forceinline__ float bf2f(unsigned short u) {
    union { unsigned int i; float f; } c;
    c.i = ((unsigned int)u) << 16;
    return c.f;
}
__device__ __forceinline__ unsigned short f2bf(float f) {
    unsigned int i = __float_as_uint(f);
    unsigned int r = (i + 0x7fffu + ((i >> 16) & 1u)) >> 16;   // RNE
    return (unsigned short)r;
}

// ---- rank pass: deg histogram + per-edge rank in one pass ----
__global__ void k_rank(const int* __restrict__ dst, int* __restrict__ deg,
                       int* __restrict__ rnk) {
    int e = blockIdx.x * 256 + threadIdx.x;
    if (e < N_EDGES) rnk[e] = atomicAdd(&deg[dst[e]], 1);
}

// ---- scan1: block-local exclusive scan of deg + dinv ----
__global__ void k_scan1(const int* __restrict__ deg, int* __restrict__ rowptr,
                        int* __restrict__ bsum, float* __restrict__ dinv) {
    __shared__ int s[256];
    int tid = threadIdx.x;
    int i = blockIdx.x * 256 + tid;
    int v = (i < N_NODES) ? deg[i] : 0;
    if (i < N_NODES) dinv[i] = rsqrtf((float)(v + 1));
    s[tid] = v;
    __syncthreads();
    for (int off = 1; off < 256; off <<= 1) {
        int t = (tid >= off) ? s[tid - off] : 0;
        __syncthreads();
        s[tid] += t;
        __syncthreads();
    }
    if (i < N_NODES) rowptr[i] = s[tid] - v;   // block-local exclusive
    if (tid == 255) bsum[blockIdx.x] = s[255];
}

// ---- scan2: exclusive scan of block sums ----
__global__ void k_scan2(const int* __restrict__ bsum, int* __restrict__ bsumx) {
    __shared__ int s[512];
    int tid = threadIdx.x;
    int v = (tid < NB_SCAN) ? bsum[tid] : 0;
    s[tid] = v;
    __syncthreads();
    for (int off = 1; off < 512; off <<= 1) {
        int t = (tid >= off) ? s[tid - off] : 0;
        __syncthreads();
        s[tid] += t;
        __syncthreads();
    }
    if (tid < NB_SCAN) bsumx[tid] = s[tid] - v;
}

// ---- place: atomic-free scatter using precomputed ranks ----
__global__ void k_place(const int* __restrict__ src, const int* __restrict__ dst,
                        const int* __restrict__ rnk, const int* __restrict__ rowptr,
                        const int* __restrict__ bsumx, int* __restrict__ eidx) {
    int e = blockIdx.x * 256 + threadIdx.x;
    if (e < N_EDGES) {
        int d = dst[e];
        eidx[rowptr[d] + bsumx[d >> 8] + rnk[e]] = src[e];
    }
}

// ---- layer-1 GEMM: hs1(bf16)[n,:] = (x[n,:] @ W1) * dinv[n] ----
__global__ __launch_bounds__(256) void k_gemm1(const float* __restrict__ x,
                                               const float* __restrict__ W1,
                                               const float* __restrict__ dinv,
                                               unsigned short* __restrict__ hs1) {
    __shared__ float sW[IN_DIM * HID];   // 32 KiB
    __shared__ float sX[32][IN_DIM];     // 16 KiB
    int node0 = blockIdx.x * 32;         // 3125 * 32 == 100000
    for (int t = threadIdx.x; t < IN_DIM * HID / 4; t += 256)
        ((float4*)sW)[t] = ((const float4*)W1)[t];
    for (int t = threadIdx.x; t < 32 * IN_DIM / 4; t += 256) {
        int r = t >> 5, c4 = t & 31;
        ((float4*)&sX[r][0])[c4] = ((const float4*)(x + (size_t)(node0 + r) * IN_DIM))[c4];
    }
    __syncthreads();
    int col = threadIdx.x & 63;
    int nb  = (threadIdx.x >> 6) * 8;
    float acc[8] = {0.f, 0.f, 0.f, 0.f, 0.f, 0.f, 0.f, 0.f};
    for (int k4 = 0; k4 < IN_DIM; k4 += 4) {
        float w0 = sW[(k4 + 0) * HID + col];
        float w1 = sW[(k4 + 1) * HID + col];
        float w2 = sW[(k4 + 2) * HID + col];
        float w3 = sW[(k4 + 3) * HID + col];
#pragma unroll
        for (int j = 0; j < 8; ++j) {
            float4 xv = *((const float4*)&sX[nb + j][k4]);
            acc[j] += xv.x * w0 + xv.y * w1 + xv.z * w2 + xv.w * w3;
        }
    }
#pragma unroll
    for (int j = 0; j < 8; ++j) {
        int n = node0 + nb + j;
        hs1[(size_t)n * HID + col] = f2bf(acc[j] * dinv[n]);
    }
}

// ---- layer-1 aggregate (bf16 gather) + epilogue + fused layer-2 GEMM ----
// W2 fragment in registers (2 KB, L1-resident) -> no LDS, no barrier, no conflicts
__global__ __launch_bounds__(256) void k_agg1(const int* __restrict__ rowptr,
                                              const int* __restrict__ bsumx,
                                              const int* __restrict__ deg,
                                              const int* __restrict__ eidx,
                                              const unsigned short* __restrict__ hs1,
                                              const float* __restrict__ dinv,
                                              const float* __restrict__ b1,
                                              const float* __restrict__ W2,
                                              float* __restrict__ hs2) {
    int node = blockIdx.x * 4 + (threadIdx.x >> 6);   // 25000 * 4 == 100000
    int lane = threadIdx.x & 63;
    int q    = lane & 15;
    int slot = lane >> 4;
    int j0   = slot * 2;
    float w20[4], w21[4];
#pragma unroll
    for (int i = 0; i < 4; ++i) {
        w20[i] = W2[(4 * q + i) * C2 + j0];
        w21[i] = W2[(4 * q + i) * C2 + j0 + 1];
    }
    int start = rowptr[node] + bsumx[node >> 8];
    int cnt   = deg[node];
    float4 acc = make_float4(0.f, 0.f, 0.f, 0.f);
    for (int k = slot; k < cnt; k += 4) {
        int s = eidx[start + k];
        ushort4 v = ((const ushort4*)(hs1 + (size_t)s * HID))[q];
        acc.x += bf2f(v.x); acc.y += bf2f(v.y);
        acc.z += bf2f(v.z); acc.w += bf2f(v.w);
    }
    acc.x += __shfl_xor(acc.x, 16); acc.y += __shfl_xor(acc.y, 16);
    acc.z += __shfl_xor(acc.z, 16); acc.w += __shfl_xor(acc.w, 16);
    acc.x += __shfl_xor(acc.x, 32); acc.y += __shfl_xor(acc.y, 32);
    acc.z += __shfl_xor(acc.z, 32); acc.w += __shfl_xor(acc.w, 32);
    ushort4 hv = ((const ushort4*)(hs1 + (size_t)node * HID))[q];
    float  di = dinv[node];
    float4 bb = ((const float4*)b1)[q];
    float4 y;
    y.x = lrelu(di * (acc.x + bf2f(hv.x)) + bb.x);
    y.y = lrelu(di * (acc.y + bf2f(hv.y)) + bb.y);
    y.z = lrelu(di * (acc.z + bf2f(hv.z)) + bb.z);
    y.w = lrelu(di * (acc.w + bf2f(hv.w)) + bb.w);
    // fused gemm2: slot s computes outputs j0, j0+1
    float p0 = y.x * w20[0] + y.y * w20[1] + y.z * w20[2] + y.w * w20[3];
    float p1 = y.x * w21[0] + y.y * w21[1] + y.z * w21[2] + y.w * w21[3];
#pragma unroll
    for (int m = 1; m < 16; m <<= 1) {
        p0 += __shfl_xor(p0, m);
        p1 += __shfl_xor(p1, m);
    }
    if (q == 0) {
        float2 r; r.x = p0 * di; r.y = p1 * di;
        ((float2*)(hs2 + (size_t)node * C2))[slot] = r;
    }
}

// ---- layer-2 aggregate + epilogue (writes y2, NO pooling) ----
__global__ __launch_bounds__(256) void k_agg2(const int* __restrict__ rowptr,
                                              const int* __restrict__ bsumx,
                                              const int* __restrict__ deg,
                                              const int* __restrict__ eidx,
                                              const float* __restrict__ hs2,
                                              const float* __restrict__ dinv,
                                              const float* __restrict__ b2,
                                              float* __restrict__ y2) {
    int node = blockIdx.x * 4 + (threadIdx.x >> 6);
    int lane = threadIdx.x & 63;
    int q    = lane & 1;
    int slot = lane >> 1;
    int start = rowptr[node] + bsumx[node >> 8];
    int cnt   = deg[node];
    float4 acc = make_float4(0.f, 0.f, 0.f, 0.f);
    for (int k = slot; k < cnt; k += 32) {
        int s = eidx[start + k];
        float4 v = ((const float4*)(hs2 + (size_t)s * C2))[q];
        acc.x += v.x; acc.y += v.y; acc.z += v.z; acc.w += v.w;
    }
    for (int m = 2; m < 64; m <<= 1) {
        acc.x += __shfl_xor(acc.x, m); acc.y += __shfl_xor(acc.y, m);
        acc.z += __shfl_xor(acc.z, m); acc.w += __shfl_xor(acc.w, m);
    }
    if (slot == 0) {
        float4 h = ((const float4*)(hs2 + (size_t)node * C2))[q];
        float di = dinv[node];
        const float* bb = b2 + q * 4;
        float4 r;
        r.x = lrelu(di * (acc.x + h.x) + bb[0]);
        r.y = lrelu(di * (acc.y + h.y) + bb[1]);
        r.z = lrelu(di * (acc.z + h.z) + bb[2]);
        r.w = lrelu(di * (acc.w + h.w) + bb[3]);
        ((float4*)(y2 + (size_t)node * C2))[q] = r;
    }
}

__device__ __forceinline__ int lower_bound(const int* __restrict__ b, int n, int v) {
    int lo = 0, hi = n;
    while (lo < hi) {
        int m = (lo + hi) >> 1;
        if (b[m] < v) lo = m + 1; else hi = m;
    }
    return lo;
}

// ---- pool + MLP: one block per graph, zero atomics ----
__global__ __launch_bounds__(256) void k_pool(const float* __restrict__ y2,
                                              const int* __restrict__ batch,
                                              const float* __restrict__ gfeat,
                                              const float* __restrict__ fcW1,
                                              const float* __restrict__ fcb1,
                                              const float* __restrict__ fcW2,
                                              const float* __restrict__ fcb2,
                                              float* __restrict__ out) {
    __shared__ float s[256];
    int g   = blockIdx.x;
    int tid = threadIdx.x;
    int start = lower_bound(batch, N_NODES, g);
    int end   = lower_bound(batch, N_NODES, g + 1);
    int col = tid & 7;
    float local = 0.f;
    for (int n = start + (tid >> 3); n < end; n += 32)
        local += y2[(size_t)n * C2 + col];
    s[tid] = local;
    __syncthreads();
    for (int off = 128; off >= 8; off >>= 1) {
        if (tid < off) s[tid] += s[tid + off];
        __syncthreads();
    }
    if (tid == 0) {
        float cnt = fmaxf((float)(end - start), 1.f);
        float z[C2 + GDIM];
        for (int c = 0; c < C2; ++c) z[c] = s[c] / cnt;
        for (int c = 0; c < GDIM; ++c) z[C2 + c] = gfeat[g * GDIM + c];
        float acc2 = fcb2[0];
        for (int j = 0; j < 16; ++j) {
            float acc = fcb1[j];
            for (int c = 0; c < C2 + GDIM; ++c) acc += z[c] * fcW1[c * 16 + j];
            acc2 += lrelu(acc) * fcW2[j];
        }
        out[g] = lrelu(acc2);
    }
}

extern "C" void kernel_launch(void* const* d_in, const int* in_sizes, int n_in,
                              void* d_out, int out_size, void* d_ws, size_t ws_size,
                              hipStream_t stream) {
    const float* x     = (const float*)d_in[0];
    const int*   ei    = (const int*)d_in[1];
    const int*   batch = (const int*)d_in[2];
    const float* gfeat = (const float*)d_in[3];
    const float* W1    = (const float*)d_in[4];
    const float* b1    = (const float*)d_in[5];
    const float* W2    = (const float*)d_in[6];
    const float* b2    = (const float*)d_in[7];
    const float* fcW1  = (const float*)d_in[8];
    const float* fcb1  = (const float*)d_in[9];
    const float* fcW2  = (const float*)d_in[10];
    const float* fcb2  = (const float*)d_in[11];
    const int* src = ei;
    const int* dst = ei + N_EDGES;

    char* ws = (char*)d_ws;
    size_t off = 0;
    auto alloc = [&](size_t bytes) -> void* {
        void* p = ws + off;
        off = (off + bytes + 255) & ~(size_t)255;
        return p;
    };
    int*   deg    = (int*)  alloc((size_t)N_NODES * 4);
    float* dinv   = (float*)alloc((size_t)N_NODES * 4);
    int*   rowptr = (int*)  alloc((size_t)N_NODES * 4);
    int*   bsum   = (int*)  alloc(512 * 4);
    int*   bsumx  = (int*)  alloc(512 * 4);
    int*   rnk    = (int*)  alloc((size_t)N_EDGES * 4);
    int*   eidx   = (int*)  alloc((size_t)N_EDGES * 4);
    unsigned short* hs1 = (unsigned short*)alloc((size_t)N_NODES * HID * 2);
    float* hs2    = (float*)alloc((size_t)N_NODES * C2 * 4);
    float* y2     = (float*)alloc((size_t)N_NODES * C2 * 4);

    hipMemsetAsync(deg, 0, (size_t)N_NODES * 4, stream);

    k_rank <<<(N_EDGES + 255) / 256, 256, 0, stream>>>(dst, deg, rnk);
    k_scan1<<<NB_SCAN, 256, 0, stream>>>(deg, rowptr, bsum, dinv);
    k_scan2<<<1, 512, 0, stream>>>(bsum, bsumx);
    k_place<<<(N_EDGES + 255) / 256, 256, 0, stream>>>(src, dst, rnk, rowptr, bsumx, eidx);

    k_gemm1<<<N_NODES / 32, 256, 0, stream>>>(x, W1, dinv, hs1);
    k_agg1 <<<N_NODES / 4, 256, 0, stream>>>(rowptr, bsumx, deg, eidx, hs1, dinv, b1, W2, hs2);
    k_agg2 <<<N_NODES / 4, 256, 0, stream>>>(rowptr, bsumx, deg, eidx, hs2, dinv, b2, y2);
    k_pool <<<NG, 256, 0, stream>>>(y2, batch, gfeat, fcW1, fcb1, fcW2, fcb2, (float*)d_out);
}

// Round 6
// 278.498 us; speedup vs baseline: 1.7596x; 1.0734x over previous
//
#include <hip/hip_runtime.h>

constexpr int N_NODES = 100000;
constexpr int N_EDGES = 1600000;
constexpr int IN_DIM  = 128;
constexpr int HID     = 64;
constexpr int C2      = 8;
constexpr int GDIM    = 24;
constexpr int NG      = 64;
constexpr float SLOPE = 0.01f;
constexpr int NB_SCAN = (N_NODES + 255) / 256;   // 391

__device__ __forceinline__ float lrelu(float v) { return v > 0.f ? v : SLOPE * v; }

__device__ __forceinline__ float bflo(unsigned int u) { return __uint_as_float(u << 16); }
__device__ __forceinline__ float bfhi(unsigned int u) { return __uint_as_float(u & 0xffff0000u); }
__device__ __forceinline__ unsigned short f2bf(float f) {
    unsigned int i = __float_as_uint(f);
    unsigned int r = (i + 0x7fffu + ((i >> 16) & 1u)) >> 16;   // RNE
    return (unsigned short)r;
}

// ---- rank pass: deg histogram + per-edge rank in one pass ----
__global__ void k_rank(const int* __restrict__ dst, int* __restrict__ deg,
                       int* __restrict__ rnk) {
    int e = blockIdx.x * 256 + threadIdx.x;
    if (e < N_EDGES) rnk[e] = atomicAdd(&deg[dst[e]], 1);
}

// ---- scan1: block-local exclusive scan of deg + dinv ----
__global__ void k_scan1(const int* __restrict__ deg, int* __restrict__ rowptr,
                        int* __restrict__ bsum, float* __restrict__ dinv) {
    __shared__ int s[256];
    int tid = threadIdx.x;
    int i = blockIdx.x * 256 + tid;
    int v = (i < N_NODES) ? deg[i] : 0;
    if (i < N_NODES) dinv[i] = rsqrtf((float)(v + 1));
    s[tid] = v;
    __syncthreads();
    for (int off = 1; off < 256; off <<= 1) {
        int t = (tid >= off) ? s[tid - off] : 0;
        __syncthreads();
        s[tid] += t;
        __syncthreads();
    }
    if (i < N_NODES) rowptr[i] = s[tid] - v;   // block-local exclusive
    if (tid == 255) bsum[blockIdx.x] = s[255];
}

// ---- scan2: exclusive scan of block sums ----
__global__ void k_scan2(const int* __restrict__ bsum, int* __restrict__ bsumx) {
    __shared__ int s[512];
    int tid = threadIdx.x;
    int v = (tid < NB_SCAN) ? bsum[tid] : 0;
    s[tid] = v;
    __syncthreads();
    for (int off = 1; off < 512; off <<= 1) {
        int t = (tid >= off) ? s[tid - off] : 0;
        __syncthreads();
        s[tid] += t;
        __syncthreads();
    }
    if (tid < NB_SCAN) bsumx[tid] = s[tid] - v;
}

// ---- place: atomic-free scatter using precomputed ranks ----
__global__ void k_place(const int* __restrict__ src, const int* __restrict__ dst,
                        const int* __restrict__ rnk, const int* __restrict__ rowptr,
                        const int* __restrict__ bsumx, int* __restrict__ eidx) {
    int e = blockIdx.x * 256 + threadIdx.x;
    if (e < N_EDGES) {
        int d = dst[e];
        eidx[rowptr[d] + bsumx[d >> 8] + rnk[e]] = src[e];
    }
}

// ---- layer-1 GEMM: hs1(bf16)[n,:] = (x[n,:] @ W1) * dinv[n] ----
__global__ __launch_bounds__(256) void k_gemm1(const float* __restrict__ x,
                                               const float* __restrict__ W1,
                                               const float* __restrict__ dinv,
                                               unsigned short* __restrict__ hs1) {
    __shared__ float sW[IN_DIM * HID];   // 32 KiB
    __shared__ float sX[32][IN_DIM];     // 16 KiB
    int node0 = blockIdx.x * 32;         // 3125 * 32 == 100000
    for (int t = threadIdx.x; t < IN_DIM * HID / 4; t += 256)
        ((float4*)sW)[t] = ((const float4*)W1)[t];
    for (int t = threadIdx.x; t < 32 * IN_DIM / 4; t += 256) {
        int r = t >> 5, c4 = t & 31;
        ((float4*)&sX[r][0])[c4] = ((const float4*)(x + (size_t)(node0 + r) * IN_DIM))[c4];
    }
    __syncthreads();
    int col = threadIdx.x & 63;
    int nb  = (threadIdx.x >> 6) * 8;
    float acc[8] = {0.f, 0.f, 0.f, 0.f, 0.f, 0.f, 0.f, 0.f};
    for (int k4 = 0; k4 < IN_DIM; k4 += 4) {
        float w0 = sW[(k4 + 0) * HID + col];
        float w1 = sW[(k4 + 1) * HID + col];
        float w2 = sW[(k4 + 2) * HID + col];
        float w3 = sW[(k4 + 3) * HID + col];
#pragma unroll
        for (int j = 0; j < 8; ++j) {
            float4 xv = *((const float4*)&sX[nb + j][k4]);
            acc[j] += xv.x * w0 + xv.y * w1 + xv.z * w2 + xv.w * w3;
        }
    }
#pragma unroll
    for (int j = 0; j < 8; ++j) {
        int n = node0 + nb + j;
        hs1[(size_t)n * HID + col] = f2bf(acc[j] * dinv[n]);
    }
}

// ---- layer-1 aggregate + epilogue + fused layer-2 GEMM ----
// 8 slots x 8 col-groups; each lane loads 16B (8 bf16); idx preloaded + shfl
__global__ __launch_bounds__(256) void k_agg1(const int* __restrict__ rowptr,
                                              const int* __restrict__ bsumx,
                                              const int* __restrict__ deg,
                                              const int* __restrict__ eidx,
                                              const unsigned short* __restrict__ hs1,
                                              const float* __restrict__ dinv,
                                              const float* __restrict__ b1,
                                              const float* __restrict__ W2,
                                              float* __restrict__ hs2) {
    int node = blockIdx.x * 4 + (threadIdx.x >> 6);   // 25000 * 4 == 100000
    int lane = threadIdx.x & 63;
    int q    = lane & 7;     // columns 8q..8q+7
    int slot = lane >> 3;    // 8 edge slots
    // W2 fragment: lane needs W2[8q+i][slot], i=0..7
    float w2f[8];
#pragma unroll
    for (int i = 0; i < 8; ++i) w2f[i] = W2[(8 * q + i) * C2 + slot];
    int start = rowptr[node] + bsumx[node >> 8];
    int cnt   = deg[node];
    float acc[8] = {0.f, 0.f, 0.f, 0.f, 0.f, 0.f, 0.f, 0.f};
    for (int base = 0; base < cnt; base += 64) {
        int idx = (base + lane < cnt) ? eidx[start + base + lane] : 0;
        int lim = min(64, cnt - base);
        for (int k = slot; k < lim; k += 8) {
            int s = __shfl(idx, k);
            uint4 v = ((const uint4*)(hs1 + (size_t)s * HID))[q];
            acc[0] += bflo(v.x); acc[1] += bfhi(v.x);
            acc[2] += bflo(v.y); acc[3] += bfhi(v.y);
            acc[4] += bflo(v.z); acc[5] += bfhi(v.z);
            acc[6] += bflo(v.w); acc[7] += bfhi(v.w);
        }
    }
    // butterfly across slot bits (8,16,32) -> all lanes hold full column sums
#pragma unroll
    for (int m = 8; m < 64; m <<= 1)
#pragma unroll
        for (int i = 0; i < 8; ++i) acc[i] += __shfl_xor(acc[i], m);
    uint4 hv = ((const uint4*)(hs1 + (size_t)node * HID))[q];
    float self[8] = {bflo(hv.x), bfhi(hv.x), bflo(hv.y), bfhi(hv.y),
                     bflo(hv.z), bfhi(hv.z), bflo(hv.w), bfhi(hv.w)};
    float di = dinv[node];
    float4 bb0 = ((const float4*)b1)[2 * q];
    float4 bb1 = ((const float4*)b1)[2 * q + 1];
    float bv[8] = {bb0.x, bb0.y, bb0.z, bb0.w, bb1.x, bb1.y, bb1.z, bb1.w};
    float p = 0.f;
#pragma unroll
    for (int i = 0; i < 8; ++i) {
        float y = lrelu(di * (acc[i] + self[i]) + bv[i]);
        p += y * w2f[i];
    }
    // reduce over q bits (1,2,4)
#pragma unroll
    for (int m = 1; m < 8; m <<= 1) p += __shfl_xor(p, m);
    if (q == 0) hs2[(size_t)node * C2 + slot] = p * di;
}

// ---- layer-2 aggregate + epilogue (writes y2) ----
__global__ __launch_bounds__(256) void k_agg2(const int* __restrict__ rowptr,
                                              const int* __restrict__ bsumx,
                                              const int* __restrict__ deg,
                                              const int* __restrict__ eidx,
                                              const float* __restrict__ hs2,
                                              const float* __restrict__ dinv,
                                              const float* __restrict__ b2,
                                              float* __restrict__ y2) {
    int node = blockIdx.x * 4 + (threadIdx.x >> 6);
    int lane = threadIdx.x & 63;
    int q    = lane & 1;
    int slot = lane >> 1;
    int start = rowptr[node] + bsumx[node >> 8];
    int cnt   = deg[node];
    float4 acc = make_float4(0.f, 0.f, 0.f, 0.f);
    for (int base = 0; base < cnt; base += 64) {
        int idx = (base + lane < cnt) ? eidx[start + base + lane] : 0;
        int lim = min(64, cnt - base);
        for (int k = slot; k < lim; k += 32) {
            int s = __shfl(idx, k);
            float4 v = ((const float4*)(hs2 + (size_t)s * C2))[q];
            acc.x += v.x; acc.y += v.y; acc.z += v.z; acc.w += v.w;
        }
    }
    for (int m = 2; m < 64; m <<= 1) {
        acc.x += __shfl_xor(acc.x, m); acc.y += __shfl_xor(acc.y, m);
        acc.z += __shfl_xor(acc.z, m); acc.w += __shfl_xor(acc.w, m);
    }
    if (slot == 0) {
        float4 h = ((const float4*)(hs2 + (size_t)node * C2))[q];
        float di = dinv[node];
        const float* bb = b2 + q * 4;
        float4 r;
        r.x = lrelu(di * (acc.x + h.x) + bb[0]);
        r.y = lrelu(di * (acc.y + h.y) + bb[1]);
        r.z = lrelu(di * (acc.z + h.z) + bb[2]);
        r.w = lrelu(di * (acc.w + h.w) + bb[3]);
        ((float4*)(y2 + (size_t)node * C2))[q] = r;
    }
}

__device__ __forceinline__ int lower_bound(const int* __restrict__ b, int n, int v) {
    int lo = 0, hi = n;
    while (lo < hi) {
        int m = (lo + hi) >> 1;
        if (b[m] < v) lo = m + 1; else hi = m;
    }
    return lo;
}

// ---- pool + MLP: one block per graph, zero atomics ----
__global__ __launch_bounds__(256) void k_pool(const float* __restrict__ y2,
                                              const int* __restrict__ batch,
                                              const float* __restrict__ gfeat,
                                              const float* __restrict__ fcW1,
                                              const float* __restrict__ fcb1,
                                              const float* __restrict__ fcW2,
                                              const float* __restrict__ fcb2,
                                              float* __restrict__ out) {
    __shared__ float s[256];
    int g   = blockIdx.x;
    int tid = threadIdx.x;
    int start = lower_bound(batch, N_NODES, g);
    int end   = lower_bound(batch, N_NODES, g + 1);
    int col = tid & 7;
    float local = 0.f;
    for (int n = start + (tid >> 3); n < end; n += 32)
        local += y2[(size_t)n * C2 + col];
    s[tid] = local;
    __syncthreads();
    for (int off = 128; off >= 8; off >>= 1) {
        if (tid < off) s[tid] += s[tid + off];
        __syncthreads();
    }
    if (tid == 0) {
        float cnt = fmaxf((float)(end - start), 1.f);
        float z[C2 + GDIM];
        for (int c = 0; c < C2; ++c) z[c] = s[c] / cnt;
        for (int c = 0; c < GDIM; ++c) z[C2 + c] = gfeat[g * GDIM + c];
        float acc2 = fcb2[0];
        for (int j = 0; j < 16; ++j) {
            float acc = fcb1[j];
            for (int c = 0; c < C2 + GDIM; ++c) acc += z[c] * fcW1[c * 16 + j];
            acc2 += lrelu(acc) * fcW2[j];
        }
        out[g] = lrelu(acc2);
    }
}

extern "C" void kernel_launch(void* const* d_in, const int* in_sizes, int n_in,
                              void* d_out, int out_size, void* d_ws, size_t ws_size,
                              hipStream_t stream) {
    const float* x     = (const float*)d_in[0];
    const int*   ei    = (const int*)d_in[1];
    const int*   batch = (const int*)d_in[2];
    const float* gfeat = (const float*)d_in[3];
    const float* W1    = (const float*)d_in[4];
    const float* b1    = (const float*)d_in[5];
    const float* W2    = (const float*)d_in[6];
    const float* b2    = (const float*)d_in[7];
    const float* fcW1  = (const float*)d_in[8];
    const float* fcb1  = (const float*)d_in[9];
    const float* fcW2  = (const float*)d_in[10];
    const float* fcb2  = (const float*)d_in[11];
    const int* src = ei;
    const int* dst = ei + N_EDGES;

    char* ws = (char*)d_ws;
    size_t off = 0;
    auto alloc = [&](size_t bytes) -> void* {
        void* p = ws + off;
        off = (off + bytes + 255) & ~(size_t)255;
        return p;
    };
    int*   deg    = (int*)  alloc((size_t)N_NODES * 4);
    float* dinv   = (float*)alloc((size_t)N_NODES * 4);
    int*   rowptr = (int*)  alloc((size_t)N_NODES * 4);
    int*   bsum   = (int*)  alloc(512 * 4);
    int*   bsumx  = (int*)  alloc(512 * 4);
    int*   rnk    = (int*)  alloc((size_t)N_EDGES * 4);
    int*   eidx   = (int*)  alloc((size_t)N_EDGES * 4);
    unsigned short* hs1 = (unsigned short*)alloc((size_t)N_NODES * HID * 2);
    float* hs2    = (float*)alloc((size_t)N_NODES * C2 * 4);
    float* y2     = (float*)alloc((size_t)N_NODES * C2 * 4);

    hipMemsetAsync(deg, 0, (size_t)N_NODES * 4, stream);

    k_rank <<<(N_EDGES + 255) / 256, 256, 0, stream>>>(dst, deg, rnk);
    k_scan1<<<NB_SCAN, 256, 0, stream>>>(deg, rowptr, bsum, dinv);
    k_scan2<<<1, 512, 0, stream>>>(bsum, bsumx);
    k_place<<<(N_EDGES + 255) / 256, 256, 0, stream>>>(src, dst, rnk, rowptr, bsumx, eidx);

    k_gemm1<<<N_NODES / 32, 256, 0, stream>>>(x, W1, dinv, hs1);
    k_agg1 <<<N_NODES / 4, 256, 0, stream>>>(rowptr, bsumx, deg, eidx, hs1, dinv, b1, W2, hs2);
    k_agg2 <<<N_NODES / 4, 256, 0, stream>>>(rowptr, bsumx, deg, eidx, hs2, dinv, b2, y2);
    k_pool <<<NG, 256, 0, stream>>>(y2, batch, gfeat, fcW1, fcb1, fcW2, fcb2, (float*)d_out);
}